// Round 16
// baseline (82.077 us; speedup 1.0000x reference)
//
#include <hip/hip_runtime.h>

#define Bn 2
#define Cn 64
#define Hn 224
#define Wn 224
#define HWn (Hn*Wn)
#define WSn 32
#define OVn 8
#define STRIDEn 24
#define NHn 9
#define NWn 9
#define NWT 28                 // W/8 tiles per row
#define VROW (NWT*Cn*8)        // 14336 elements per (b,h) row in vb2
#define QSCALE (1.44269504088896f/32.0f)

typedef __bf16 bf16x8 __attribute__((ext_vector_type(8)));
typedef __bf16 bf16x4 __attribute__((ext_vector_type(4)));
typedef float f32x16 __attribute__((ext_vector_type(16)));
typedef unsigned int uint4v __attribute__((ext_vector_type(4)));

union PackU { uint4v u; bf16x8 h; };
union BfPair { __bf16 h[2]; unsigned u; };

// Schraudolph 2-op exp2: as_float((int)(x*2^23 + (127*2^23 - 366900))).
// +-3% pointwise, but P is cast to bf16 anyway and softmax numerator/
// denominator errors cancel (scores here are small: |x| < ~2, P in
// [0.57,1.74], near-uniform weights -> net output error ~0.2%). Two
// FULL-RATE VALU ops replace one quarter-rate trans op + hazard waits.
__device__ __forceinline__ float sexp2(float x) {
  return __int_as_float((int)fmaf(x, 8388608.0f, 1064986316.0f));
}

__device__ __forceinline__ float fast_rcp(float x) {
#if __has_builtin(__builtin_amdgcn_rcpf)
  return __builtin_amdgcn_rcpf(x);
#else
  return 1.0f / x;
#endif
}

// fade weight factor for window index i, in-window position p
__device__ __forceinline__ float edge_w(int i, int p) {
  float w = 1.0f;
  if (i > 0 && p < OVn)            w *= (float)p * (1.0f/7.0f);
  if (i < NHn-1 && p >= WSn-OVn)   w *= (float)(WSn-1-p) * (1.0f/7.0f);
  return w;
}

// separable coverage sum
__device__ __forceinline__ float covsum(int h) {
  int ihi = h / STRIDEn; if (ihi > NHn-1) ihi = NHn-1;
  float s = edge_w(ihi, h - STRIDEn*ihi);
  int ilo = ihi - 1;
  if (ilo >= 0) {
    int p = h - STRIDEn*ilo;
    if (p < WSn) s += edge_w(ilo, p);
  }
  return s;
}

// ---------------- QKV projection via MFMA ----------------
// C[80 x 100352] = Wall[80 x 64] * X[64 x 100352], one wave = 32 pixels.
__global__ __launch_bounds__(256) void qkv_kernel(
    const float* __restrict__ x,
    const float* __restrict__ Wq, const float* __restrict__ bq,
    const float* __restrict__ Wk, const float* __restrict__ bk,
    const float* __restrict__ Wv, const float* __restrict__ bv,
    __bf16* __restrict__ qb, __bf16* __restrict__ kb, __bf16* __restrict__ vb2)
{
  __shared__ __attribute__((aligned(16))) __bf16 sA[3][4][64][8];  // 12 KB A-frags
  __shared__ float sBias[96];
  __shared__ float sT[4][32*17];                                   // per-wave q/k transpose

  int tid = threadIdx.x;
  for (int f = tid; f < 768; f += 256) {
    int t = f >> 8;
    int rem = f & 255;
    int s = rem >> 6;
    int ln = rem & 63;
    int row = t*32 + (ln & 31);
    int ch  = s*16 + (ln >> 5)*8;
    const float* src = nullptr;
    float scale = 1.0f;
    if (row < 8)       { src = Wq + row*64 + ch; scale = QSCALE; }
    else if (row < 16) { src = Wk + (row-8)*64 + ch; }
    else if (row < 80) { src = Wv + (row-16)*64 + ch; }
    bf16x8 a = {};
    if (src) {
      #pragma unroll
      for (int j = 0; j < 8; ++j) a[j] = (__bf16)(src[j] * scale);
    }
    *(bf16x8*)&sA[t][s][ln][0] = a;
  }
  if (tid < 96) {
    float bb = 0.f;
    if (tid < 8)       bb = bq[tid] * QSCALE;
    else if (tid < 16) bb = bk[tid-8];
    else if (tid < 80) bb = bv[tid-16];
    sBias[tid] = bb;
  }
  __syncthreads();

  int widx = tid >> 6;
  int lane = tid & 63;
  int lo = lane & 31, hi = lane >> 5;
  int gid = blockIdx.x*4 + widx;        // 3136 wave-groups = 2*224*7
  int wg  = gid % 7;
  int rem = gid / 7;
  int h = rem % Hn;
  int b = rem / Hn;
  int w0 = wg * 32;
  const float* xb = x + (size_t)b*Cn*HWn + (size_t)h*Wn + w0 + lo;

  f32x16 d0 = {}, d1 = {}, d2 = {};
  #pragma unroll
  for (int s = 0; s < 4; ++s) {
    bf16x8 bfr;
    #pragma unroll
    for (int j = 0; j < 8; ++j)
      bfr[j] = (__bf16)xb[(size_t)(s*16 + 8*hi + j)*HWn];
    bf16x8 a0 = *(const bf16x8*)&sA[0][s][lane][0];
    bf16x8 a1 = *(const bf16x8*)&sA[1][s][lane][0];
    bf16x8 a2 = *(const bf16x8*)&sA[2][s][lane][0];
    d0 = __builtin_amdgcn_mfma_f32_32x32x16_bf16(a0, bfr, d0, 0, 0, 0);
    d1 = __builtin_amdgcn_mfma_f32_32x32x16_bf16(a1, bfr, d1, 0, 0, 0);
    d2 = __builtin_amdgcn_mfma_f32_32x32x16_bf16(a2, bfr, d2, 0, 0, 0);
  }

  float* T = sT[widx];
  #pragma unroll
  for (int r = 0; r < 8; ++r) {
    int row = (r&3) + 8*(r>>2) + 4*hi;          // 0..15
    T[lo*17 + row] = d0[r] + sBias[row];
  }
  __syncthreads();
  PackU o;
  #pragma unroll
  for (int m = 0; m < 8; ++m) o.h[m] = (__bf16)T[lo*17 + hi*8 + m];
  size_t pix = (size_t)(b*Hn + h)*Wn + w0 + lo;
  if (hi == 0) *(uint4v*)(qb + pix*8) = o.u;
  else         *(uint4v*)(kb + pix*8) = o.u;

  __bf16* vbl = vb2 + ((size_t)(b*Hn + h)*NWT + (w0>>3))*(Cn*8)
                + (size_t)(lo>>3)*(Cn*8) + (lo&7);
  #pragma unroll
  for (int r = 8; r < 16; ++r) {
    int row = (r&3) + 8*(r>>2) + 4*hi;          // 16..31
    vbl[(size_t)(row-16)*8] = (__bf16)(d0[r] + sBias[row]);
  }
  #pragma unroll
  for (int r = 0; r < 16; ++r) {
    int row = 32 + (r&3) + 8*(r>>2) + 4*hi;     // 32..63
    vbl[(size_t)(row-16)*8] = (__bf16)(d1[r] + sBias[row]);
  }
  #pragma unroll
  for (int r = 0; r < 8; ++r) {
    int row = 64 + (r&3) + 8*(r>>2) + 4*hi;     // 64..79
    vbl[(size_t)(row-16)*8] = (__bf16)(d2[r] + sBias[row]);
  }
}

// ---------------- MFMA flash attention ----------------
// One wave = (window, query-row ph): all 1024 keys, fully independent.
// Block = 256 threads = 4 waves; grid = 162*8 = 1296 blocks. r12 structure
// (best measured: 54.0us, VGPR 48); this round's single change: Schraudolph
// 2-op exp2 replaces v_exp_f32 — the trans-pipe stream (2.65M quarter-rate
// ops + hazard waits) is the one term every prior variant held constant.
__global__ __launch_bounds__(256, 4) void attn_kernel(
    const __bf16* __restrict__ qb, const __bf16* __restrict__ kb,
    const __bf16* __restrict__ vb2, __bf16* __restrict__ ob2)
{
  __shared__ float LB[4*1056];    // per-wave [32][33] transpose tile (16.9 KB)

  // XCD swizzle: 1296 = 8*162; all 8 blocks of a window land on one XCD.
  int bid = blockIdx.x;
  int bidm = (bid & 7) * 162 + (bid >> 3);
  int win = bidm >> 3;            // 0..161
  int rg  = bidm & 7;             // row-group 0..7
  int b  = win / (NHn*NWn);
  int ij = win - b*(NHn*NWn);
  int wi = ij / NWn;
  int wj = ij - wi*NWn;

  int tid  = threadIdx.x;
  int widx = tid >> 6;            // wave 0..3
  int lane = tid & 63;
  int ph = rg*4 + widx;           // query row 0..31
  int lo = lane & 31, hi = lane >> 5;
  int h0 = wi*STRIDEn, w0 = wj*STRIDEn;

  // Q fragment (B operand): lane holds Q[query=lo][ch=8*hi+j]; hi lanes zeroed
  bf16x8 qf = *(const bf16x8*)(qb + ((size_t)(b*Hn + h0 + ph)*Wn + w0 + lo) * 8);
  if (hi) qf = (bf16x8){};

  const __bf16* kbase = kb + ((size_t)(b*Hn + h0)*Wn + w0 + lo) * 8;
  const __bf16* vbase = vb2 + (((size_t)(b*Hn + h0)*NWT + (w0>>3))*Cn + lo)*8
                        + (size_t)hi*512;

  f32x16 acc0 = {}, acc1 = {};
  float ls[4] = {0.f, 0.f, 0.f, 0.f};   // partial sums break the serial add chain

  #pragma unroll 4
  for (int kt = 0; kt < 32; ++kt) {
    bf16x8 kf = *(const bf16x8*)(kbase + (size_t)kt*Wn*8);

    const __bf16* vk = vbase + (size_t)kt*VROW;
    bf16x8 vf00 = *(const bf16x8*)(vk);           // keys 8*hi+j,    ch lo
    bf16x8 vf01 = *(const bf16x8*)(vk + 256);     // keys 8*hi+j,    ch lo+32
    bf16x8 vf10 = *(const bf16x8*)(vk + 1024);    // keys 16+8*hi+j, ch lo
    bf16x8 vf11 = *(const bf16x8*)(vk + 1280);    // keys 16+8*hi+j, ch lo+32

    // S[key][query]: key=(r&3)+8*(r>>2)+4*hi, query=lo. log2 domain.
    f32x16 s = __builtin_amdgcn_mfma_f32_32x32x16_bf16(kf, qf, (f32x16){}, 0, 0, 0);

    unsigned w[8];
    #pragma unroll
    for (int d = 0; d < 8; ++d) {
      float a  = sexp2(s[2*d]);
      float b2 = sexp2(s[2*d+1]);
      ls[d & 3] += a + b2;
      BfPair pr; pr.h[0] = (__bf16)a; pr.h[1] = (__bf16)b2;
      w[d] = pr.u;
    }
    // permlane32_swap: one op yields BOTH PV-fragment words.
    auto s02 = __builtin_amdgcn_permlane32_swap((int)w[0], (int)w[2], false, false);
    auto s13 = __builtin_amdgcn_permlane32_swap((int)w[1], (int)w[3], false, false);
    auto s46 = __builtin_amdgcn_permlane32_swap((int)w[4], (int)w[6], false, false);
    auto s57 = __builtin_amdgcn_permlane32_swap((int)w[5], (int)w[7], false, false);

    PackU pa0, pa1;
    pa0.u = (uint4v){(unsigned)s02[0], (unsigned)s13[0], (unsigned)s02[1], (unsigned)s13[1]};
    pa1.u = (uint4v){(unsigned)s46[0], (unsigned)s57[0], (unsigned)s46[1], (unsigned)s57[1]};

    __builtin_amdgcn_s_setprio(1);
    acc0 = __builtin_amdgcn_mfma_f32_32x32x16_bf16(pa0.h, vf00, acc0, 0, 0, 0);
    acc1 = __builtin_amdgcn_mfma_f32_32x32x16_bf16(pa0.h, vf01, acc1, 0, 0, 0);
    acc0 = __builtin_amdgcn_mfma_f32_32x32x16_bf16(pa1.h, vf10, acc0, 0, 0, 0);
    acc1 = __builtin_amdgcn_mfma_f32_32x32x16_bf16(pa1.h, vf11, acc1, 0, 0, 0);
    __builtin_amdgcn_s_setprio(0);
  }

  float lsum = (ls[0] + ls[1]) + (ls[2] + ls[3]);
  // partner half-wave holds the complementary key set for the same query lo
  lsum += __shfl_xor(lsum, 32);
  float sc = edge_w(wi, ph) * edge_w(wj, lo) * fast_rcp(lsum);  // lane's query col = lo

  // per-wave sequential transpose: acc layout D[qc=(r&3)+8*(r>>2)+4*hi][ch=lo]
  float* T = LB + (size_t)widx*1056;    // [32][33]
  __bf16* ob = ob2 + ((size_t)win*64)*1024 + ph*32;  // [win][c][p], p=ph*32+qc

  #pragma unroll
  for (int r = 0; r < 16; ++r) {
    int qc = (r&3) + 8*(r>>2) + 4*hi;
    T[qc*33 + lo] = acc0[r];
  }
  #pragma unroll
  for (int rr = 0; rr < 16; ++rr) {
    int c0 = 2*rr + hi;
    ob[(size_t)c0*1024 + lo] = (__bf16)(T[lo*33 + c0] * sc);
  }
  #pragma unroll
  for (int r = 0; r < 16; ++r) {
    int qc = (r&3) + 8*(r>>2) + 4*hi;
    T[qc*33 + lo] = acc1[r];
  }
  #pragma unroll
  for (int rr = 0; rr < 16; ++rr) {
    int c0 = 2*rr + hi;
    ob[(size_t)(32 + c0)*1024 + lo] = (__bf16)(T[lo*33 + c0] * sc);
  }
}

// ---------------- final blend: gather <=4 window contributions ----------------
__global__ __launch_bounds__(256) void final_kernel(
    const float* __restrict__ x, const float* __restrict__ gamma,
    const __bf16* __restrict__ ob2, float* __restrict__ out)
{
  int idx4 = blockIdx.x * 256 + threadIdx.x;   // < B*C*H*W/4
  int w4    = idx4 % (Wn/4);
  int rowid = idx4 / (Wn/4);
  int h  = rowid % Hn;
  int cb = rowid / Hn;          // b*64 + c
  int c  = cb & 63;
  int b  = cb >> 6;
  int w0 = w4*4;

  int ihi = h  / STRIDEn; if (ihi > NHn-1) ihi = NHn-1;
  int jhi = w0 / STRIDEn; if (jhi > NWn-1) jhi = NWn-1;

  float s0 = 0.f, s1 = 0.f, s2 = 0.f, s3 = 0.f;
  #pragma unroll
  for (int dy = 0; dy < 2; ++dy) {
    int wi = ihi - dy;
    if (wi < 0) continue;
    int ph = h - STRIDEn*wi;
    if (ph >= WSn) continue;
    #pragma unroll
    for (int dx = 0; dx < 2; ++dx) {
      int wj = jhi - dx;
      if (wj < 0) continue;
      int pw = w0 - STRIDEn*wj;
      if (pw >= WSn) continue;
      const __bf16* src = ob2 + (((size_t)(b*81 + wi*9 + wj)*64 + c) << 10) + ph*WSn + pw;
      bf16x4 v = *(const bf16x4*)src;
      s0 += (float)v[0]; s1 += (float)v[1]; s2 += (float)v[2]; s3 += (float)v[3];
    }
  }

  float g = gamma[0];
  float rs = covsum(h);
  float i0 = fast_rcp(rs * covsum(w0+0) + 1e-8f);
  float i1 = fast_rcp(rs * covsum(w0+1) + 1e-8f);
  float i2 = fast_rcp(rs * covsum(w0+2) + 1e-8f);
  float i3 = fast_rcp(rs * covsum(w0+3) + 1e-8f);
  float4 xv = ((const float4*)x)[idx4];
  float4 r;
  r.x = xv.x + g * s0 * i0;
  r.y = xv.y + g * s1 * i1;
  r.z = xv.z + g * s2 * i2;
  r.w = xv.w + g * s3 * i3;
  ((float4*)out)[idx4] = r;
}

extern "C" void kernel_launch(void* const* d_in, const int* in_sizes, int n_in,
                              void* d_out, int out_size, void* d_ws, size_t ws_size,
                              hipStream_t stream) {
  const float* x     = (const float*)d_in[0];
  const float* Wq    = (const float*)d_in[1];
  const float* bq    = (const float*)d_in[2];
  const float* Wk    = (const float*)d_in[3];
  const float* bk    = (const float*)d_in[4];
  const float* Wv    = (const float*)d_in[5];
  const float* bv    = (const float*)d_in[6];
  const float* gamma = (const float*)d_in[7];
  float* out = (float*)d_out;

  __bf16* qb  = (__bf16*)d_ws;                       // B*H*W*8          (1.6 MB)
  __bf16* kb  = qb  + (size_t)Bn*HWn*8;              // B*H*W*8          (1.6 MB)
  __bf16* vb2 = kb  + (size_t)Bn*HWn*8;              // B*C*H*W w8-tiled (12.8 MB)
  __bf16* ob2 = vb2 + (size_t)Bn*Cn*HWn;             // 162*64*1024      (21.2 MB)

  qkv_kernel<<<784, 256, 0, stream>>>(x, Wq, bq, Wk, bk, Wv, bv, qb, kb, vb2);
  attn_kernel<<<Bn*NHn*NWn*8, 256, 0, stream>>>(qb, kb, vb2, ob2);
  final_kernel<<<(Bn*Cn*HWn/4)/256, 256, 0, stream>>>(x, gamma, ob2, out);
}

// Round 17
// 79.837 us; speedup vs baseline: 1.0281x; 1.0281x over previous
//
#include <hip/hip_runtime.h>

#define Bn 2
#define Cn 64
#define Hn 224
#define Wn 224
#define HWn (Hn*Wn)
#define WSn 32
#define OVn 8
#define STRIDEn 24
#define NHn 9
#define NWn 9
#define NWT 28                 // W/8 tiles per row
#define VROW (NWT*Cn*8)        // 14336 elements per (b,h) row in vb2
#define QSCALE (1.44269504088896f/32.0f)

typedef __bf16 bf16x8 __attribute__((ext_vector_type(8)));
typedef __bf16 bf16x4 __attribute__((ext_vector_type(4)));
typedef float f32x16 __attribute__((ext_vector_type(16)));
typedef unsigned int uint4v __attribute__((ext_vector_type(4)));

union PackU { uint4v u; bf16x8 h; };
union BfPair { __bf16 h[2]; unsigned u; };

__device__ __forceinline__ float fast_exp2(float x) {
#if __has_builtin(__builtin_amdgcn_exp2f)
  return __builtin_amdgcn_exp2f(x);
#else
  return exp2f(x);
#endif
}

__device__ __forceinline__ float fast_rcp(float x) {
#if __has_builtin(__builtin_amdgcn_rcpf)
  return __builtin_amdgcn_rcpf(x);
#else
  return 1.0f / x;
#endif
}

// fade weight factor for window index i, in-window position p
__device__ __forceinline__ float edge_w(int i, int p) {
  float w = 1.0f;
  if (i > 0 && p < OVn)            w *= (float)p * (1.0f/7.0f);
  if (i < NHn-1 && p >= WSn-OVn)   w *= (float)(WSn-1-p) * (1.0f/7.0f);
  return w;
}

// separable coverage sum
__device__ __forceinline__ float covsum(int h) {
  int ihi = h / STRIDEn; if (ihi > NHn-1) ihi = NHn-1;
  float s = edge_w(ihi, h - STRIDEn*ihi);
  int ilo = ihi - 1;
  if (ilo >= 0) {
    int p = h - STRIDEn*ilo;
    if (p < WSn) s += edge_w(ilo, p);
  }
  return s;
}

// ---------------- QKV projection via MFMA ----------------
// C[80 x 100352] = Wall[80 x 64] * X[64 x 100352], one wave = 32 pixels.
__global__ __launch_bounds__(256) void qkv_kernel(
    const float* __restrict__ x,
    const float* __restrict__ Wq, const float* __restrict__ bq,
    const float* __restrict__ Wk, const float* __restrict__ bk,
    const float* __restrict__ Wv, const float* __restrict__ bv,
    __bf16* __restrict__ qb, __bf16* __restrict__ kb, __bf16* __restrict__ vb2)
{
  __shared__ __attribute__((aligned(16))) __bf16 sA[3][4][64][8];  // 12 KB A-frags
  __shared__ float sBias[96];
  __shared__ float sT[4][32*17];                                   // per-wave q/k transpose

  int tid = threadIdx.x;
  for (int f = tid; f < 768; f += 256) {
    int t = f >> 8;
    int rem = f & 255;
    int s = rem >> 6;
    int ln = rem & 63;
    int row = t*32 + (ln & 31);
    int ch  = s*16 + (ln >> 5)*8;
    const float* src = nullptr;
    float scale = 1.0f;
    if (row < 8)       { src = Wq + row*64 + ch; scale = QSCALE; }
    else if (row < 16) { src = Wk + (row-8)*64 + ch; }
    else if (row < 80) { src = Wv + (row-16)*64 + ch; }
    bf16x8 a = {};
    if (src) {
      #pragma unroll
      for (int j = 0; j < 8; ++j) a[j] = (__bf16)(src[j] * scale);
    }
    *(bf16x8*)&sA[t][s][ln][0] = a;
  }
  if (tid < 96) {
    float bb = 0.f;
    if (tid < 8)       bb = bq[tid] * QSCALE;
    else if (tid < 16) bb = bk[tid-8];
    else if (tid < 80) bb = bv[tid-16];
    sBias[tid] = bb;
  }
  __syncthreads();

  int widx = tid >> 6;
  int lane = tid & 63;
  int lo = lane & 31, hi = lane >> 5;
  int gid = blockIdx.x*4 + widx;        // 3136 wave-groups = 2*224*7
  int wg  = gid % 7;
  int rem = gid / 7;
  int h = rem % Hn;
  int b = rem / Hn;
  int w0 = wg * 32;
  const float* xb = x + (size_t)b*Cn*HWn + (size_t)h*Wn + w0 + lo;

  f32x16 d0 = {}, d1 = {}, d2 = {};
  #pragma unroll
  for (int s = 0; s < 4; ++s) {
    bf16x8 bfr;
    #pragma unroll
    for (int j = 0; j < 8; ++j)
      bfr[j] = (__bf16)xb[(size_t)(s*16 + 8*hi + j)*HWn];
    bf16x8 a0 = *(const bf16x8*)&sA[0][s][lane][0];
    bf16x8 a1 = *(const bf16x8*)&sA[1][s][lane][0];
    bf16x8 a2 = *(const bf16x8*)&sA[2][s][lane][0];
    d0 = __builtin_amdgcn_mfma_f32_32x32x16_bf16(a0, bfr, d0, 0, 0, 0);
    d1 = __builtin_amdgcn_mfma_f32_32x32x16_bf16(a1, bfr, d1, 0, 0, 0);
    d2 = __builtin_amdgcn_mfma_f32_32x32x16_bf16(a2, bfr, d2, 0, 0, 0);
  }

  float* T = sT[widx];
  #pragma unroll
  for (int r = 0; r < 8; ++r) {
    int row = (r&3) + 8*(r>>2) + 4*hi;          // 0..15
    T[lo*17 + row] = d0[r] + sBias[row];
  }
  __syncthreads();
  PackU o;
  #pragma unroll
  for (int m = 0; m < 8; ++m) o.h[m] = (__bf16)T[lo*17 + hi*8 + m];
  size_t pix = (size_t)(b*Hn + h)*Wn + w0 + lo;
  if (hi == 0) *(uint4v*)(qb + pix*8) = o.u;
  else         *(uint4v*)(kb + pix*8) = o.u;

  __bf16* vbl = vb2 + ((size_t)(b*Hn + h)*NWT + (w0>>3))*(Cn*8)
                + (size_t)(lo>>3)*(Cn*8) + (lo&7);
  #pragma unroll
  for (int r = 8; r < 16; ++r) {
    int row = (r&3) + 8*(r>>2) + 4*hi;          // 16..31
    vbl[(size_t)(row-16)*8] = (__bf16)(d0[r] + sBias[row]);
  }
  #pragma unroll
  for (int r = 0; r < 16; ++r) {
    int row = 32 + (r&3) + 8*(r>>2) + 4*hi;     // 32..63
    vbl[(size_t)(row-16)*8] = (__bf16)(d1[r] + sBias[row]);
  }
  #pragma unroll
  for (int r = 0; r < 8; ++r) {
    int row = 64 + (r&3) + 8*(r>>2) + 4*hi;     // 64..79
    vbl[(size_t)(row-16)*8] = (__bf16)(d2[r] + sBias[row]);
  }
}

// ---------------- MFMA flash attention ----------------
// One wave = (window, query-row ph): all 1024 keys, fully independent.
// Block = 256 threads = 4 waves; grid = 162*8 = 1296 blocks.
// BEST MEASURED CONFIG (r12: attn 54.0us, absmax 0.0156). Falsified-variant
// ledger (all neutral-to-worse): scheduling/pipelining, fragment-order
// interchange, LDS-occupancy, nt-stores, dual-parity accs, 2-rows/wave,
// Schraudolph exp. The loop co-saturates MFMA issue + VALU issue at ~5
// waves/SIMD — balanced issue-bound; structural floor for this algorithm.
__global__ __launch_bounds__(256, 4) void attn_kernel(
    const __bf16* __restrict__ qb, const __bf16* __restrict__ kb,
    const __bf16* __restrict__ vb2, __bf16* __restrict__ ob2)
{
  __shared__ float LB[4*1056];    // per-wave [32][33] transpose tile (16.9 KB)

  // XCD swizzle: 1296 = 8*162; all 8 blocks of a window land on one XCD.
  int bid = blockIdx.x;
  int bidm = (bid & 7) * 162 + (bid >> 3);
  int win = bidm >> 3;            // 0..161
  int rg  = bidm & 7;             // row-group 0..7
  int b  = win / (NHn*NWn);
  int ij = win - b*(NHn*NWn);
  int wi = ij / NWn;
  int wj = ij - wi*NWn;

  int tid  = threadIdx.x;
  int widx = tid >> 6;            // wave 0..3
  int lane = tid & 63;
  int ph = rg*4 + widx;           // query row 0..31
  int lo = lane & 31, hi = lane >> 5;
  int h0 = wi*STRIDEn, w0 = wj*STRIDEn;

  // Q fragment (B operand): lane holds Q[query=lo][ch=8*hi+j]; hi lanes zeroed
  bf16x8 qf = *(const bf16x8*)(qb + ((size_t)(b*Hn + h0 + ph)*Wn + w0 + lo) * 8);
  if (hi) qf = (bf16x8){};

  const __bf16* kbase = kb + ((size_t)(b*Hn + h0)*Wn + w0 + lo) * 8;
  const __bf16* vbase = vb2 + (((size_t)(b*Hn + h0)*NWT + (w0>>3))*Cn + lo)*8
                        + (size_t)hi*512;

  f32x16 acc0 = {}, acc1 = {};
  float ls[4] = {0.f, 0.f, 0.f, 0.f};   // partial sums break the serial add chain

  #pragma unroll 4
  for (int kt = 0; kt < 32; ++kt) {
    bf16x8 kf = *(const bf16x8*)(kbase + (size_t)kt*Wn*8);

    const __bf16* vk = vbase + (size_t)kt*VROW;
    bf16x8 vf00 = *(const bf16x8*)(vk);           // keys 8*hi+j,    ch lo
    bf16x8 vf01 = *(const bf16x8*)(vk + 256);     // keys 8*hi+j,    ch lo+32
    bf16x8 vf10 = *(const bf16x8*)(vk + 1024);    // keys 16+8*hi+j, ch lo
    bf16x8 vf11 = *(const bf16x8*)(vk + 1280);    // keys 16+8*hi+j, ch lo+32

    // S[key][query]: key=(r&3)+8*(r>>2)+4*hi, query=lo. log2 domain.
    f32x16 s = __builtin_amdgcn_mfma_f32_32x32x16_bf16(kf, qf, (f32x16){}, 0, 0, 0);

    unsigned w[8];
    #pragma unroll
    for (int d = 0; d < 8; ++d) {
      float a  = fast_exp2(s[2*d]);
      float b2 = fast_exp2(s[2*d+1]);
      ls[d & 3] += a + b2;
      BfPair pr; pr.h[0] = (__bf16)a; pr.h[1] = (__bf16)b2;
      w[d] = pr.u;
    }
    // permlane32_swap: one op yields BOTH PV-fragment words.
    auto s02 = __builtin_amdgcn_permlane32_swap((int)w[0], (int)w[2], false, false);
    auto s13 = __builtin_amdgcn_permlane32_swap((int)w[1], (int)w[3], false, false);
    auto s46 = __builtin_amdgcn_permlane32_swap((int)w[4], (int)w[6], false, false);
    auto s57 = __builtin_amdgcn_permlane32_swap((int)w[5], (int)w[7], false, false);

    PackU pa0, pa1;
    pa0.u = (uint4v){(unsigned)s02[0], (unsigned)s13[0], (unsigned)s02[1], (unsigned)s13[1]};
    pa1.u = (uint4v){(unsigned)s46[0], (unsigned)s57[0], (unsigned)s46[1], (unsigned)s57[1]};

    __builtin_amdgcn_s_setprio(1);
    acc0 = __builtin_amdgcn_mfma_f32_32x32x16_bf16(pa0.h, vf00, acc0, 0, 0, 0);
    acc1 = __builtin_amdgcn_mfma_f32_32x32x16_bf16(pa0.h, vf01, acc1, 0, 0, 0);
    acc0 = __builtin_amdgcn_mfma_f32_32x32x16_bf16(pa1.h, vf10, acc0, 0, 0, 0);
    acc1 = __builtin_amdgcn_mfma_f32_32x32x16_bf16(pa1.h, vf11, acc1, 0, 0, 0);
    __builtin_amdgcn_s_setprio(0);
  }

  float lsum = (ls[0] + ls[1]) + (ls[2] + ls[3]);
  // partner half-wave holds the complementary key set for the same query lo
  lsum += __shfl_xor(lsum, 32);
  float sc = edge_w(wi, ph) * edge_w(wj, lo) * fast_rcp(lsum);  // lane's query col = lo

  // per-wave sequential transpose: acc layout D[qc=(r&3)+8*(r>>2)+4*hi][ch=lo]
  float* T = LB + (size_t)widx*1056;    // [32][33]
  __bf16* ob = ob2 + ((size_t)win*64)*1024 + ph*32;  // [win][c][p], p=ph*32+qc

  #pragma unroll
  for (int r = 0; r < 16; ++r) {
    int qc = (r&3) + 8*(r>>2) + 4*hi;
    T[qc*33 + lo] = acc0[r];
  }
  #pragma unroll
  for (int rr = 0; rr < 16; ++rr) {
    int c0 = 2*rr + hi;
    ob[(size_t)c0*1024 + lo] = (__bf16)(T[lo*33 + c0] * sc);
  }
  #pragma unroll
  for (int r = 0; r < 16; ++r) {
    int qc = (r&3) + 8*(r>>2) + 4*hi;
    T[qc*33 + lo] = acc1[r];
  }
  #pragma unroll
  for (int rr = 0; rr < 16; ++rr) {
    int c0 = 2*rr + hi;
    ob[(size_t)(32 + c0)*1024 + lo] = (__bf16)(T[lo*33 + c0] * sc);
  }
}

// ---------------- final blend: gather <=4 window contributions ----------------
__global__ __launch_bounds__(256) void final_kernel(
    const float* __restrict__ x, const float* __restrict__ gamma,
    const __bf16* __restrict__ ob2, float* __restrict__ out)
{
  int idx4 = blockIdx.x * 256 + threadIdx.x;   // < B*C*H*W/4
  int w4    = idx4 % (Wn/4);
  int rowid = idx4 / (Wn/4);
  int h  = rowid % Hn;
  int cb = rowid / Hn;          // b*64 + c
  int c  = cb & 63;
  int b  = cb >> 6;
  int w0 = w4*4;

  int ihi = h  / STRIDEn; if (ihi > NHn-1) ihi = NHn-1;
  int jhi = w0 / STRIDEn; if (jhi > NWn-1) jhi = NWn-1;

  float s0 = 0.f, s1 = 0.f, s2 = 0.f, s3 = 0.f;
  #pragma unroll
  for (int dy = 0; dy < 2; ++dy) {
    int wi = ihi - dy;
    if (wi < 0) continue;
    int ph = h - STRIDEn*wi;
    if (ph >= WSn) continue;
    #pragma unroll
    for (int dx = 0; dx < 2; ++dx) {
      int wj = jhi - dx;
      if (wj < 0) continue;
      int pw = w0 - STRIDEn*wj;
      if (pw >= WSn) continue;
      const __bf16* src = ob2 + (((size_t)(b*81 + wi*9 + wj)*64 + c) << 10) + ph*WSn + pw;
      bf16x4 v = *(const bf16x4*)src;
      s0 += (float)v[0]; s1 += (float)v[1]; s2 += (float)v[2]; s3 += (float)v[3];
    }
  }

  float g = gamma[0];
  float rs = covsum(h);
  float i0 = fast_rcp(rs * covsum(w0+0) + 1e-8f);
  float i1 = fast_rcp(rs * covsum(w0+1) + 1e-8f);
  float i2 = fast_rcp(rs * covsum(w0+2) + 1e-8f);
  float i3 = fast_rcp(rs * covsum(w0+3) + 1e-8f);
  float4 xv = ((const float4*)x)[idx4];
  float4 r;
  r.x = xv.x + g * s0 * i0;
  r.y = xv.y + g * s1 * i1;
  r.z = xv.z + g * s2 * i2;
  r.w = xv.w + g * s3 * i3;
  ((float4*)out)[idx4] = r;
}

extern "C" void kernel_launch(void* const* d_in, const int* in_sizes, int n_in,
                              void* d_out, int out_size, void* d_ws, size_t ws_size,
                              hipStream_t stream) {
  const float* x     = (const float*)d_in[0];
  const float* Wq    = (const float*)d_in[1];
  const float* bq    = (const float*)d_in[2];
  const float* Wk    = (const float*)d_in[3];
  const float* bk    = (const float*)d_in[4];
  const float* Wv    = (const float*)d_in[5];
  const float* bv    = (const float*)d_in[6];
  const float* gamma = (const float*)d_in[7];
  float* out = (float*)d_out;

  __bf16* qb  = (__bf16*)d_ws;                       // B*H*W*8          (1.6 MB)
  __bf16* kb  = qb  + (size_t)Bn*HWn*8;              // B*H*W*8          (1.6 MB)
  __bf16* vb2 = kb  + (size_t)Bn*HWn*8;              // B*C*H*W w8-tiled (12.8 MB)
  __bf16* ob2 = vb2 + (size_t)Bn*Cn*HWn;             // 162*64*1024      (21.2 MB)

  qkv_kernel<<<784, 256, 0, stream>>>(x, Wq, bq, Wk, bk, Wv, bv, qb, kb, vb2);
  attn_kernel<<<Bn*NHn*NWn*8, 256, 0, stream>>>(qb, kb, vb2, ob2);
  final_kernel<<<(Bn*Cn*HWn/4)/256, 256, 0, stream>>>(x, gamma, ob2, out);
}